// Round 1
// 184.334 us; speedup vs baseline: 1.0442x; 1.0442x over previous
//
#include <hip/hip_runtime.h>

#define EPS 1e-6f
#define NSTEP 63   // L = N-1 aggregation steps

typedef float vf4 __attribute__((ext_vector_type(4)));

// gfx950 builtins (avoid math.h macro clashes):
__device__ __forceinline__ float flog2(float x) { return __builtin_amdgcn_logf(x); }   // v_log_f32 = log2
__device__ __forceinline__ float fexp2(float x) { return __builtin_amdgcn_exp2f(x); }  // v_exp_f32 = 2^x
__device__ __forceinline__ float clampe1(float x) { return __builtin_amdgcn_fmed3f(x, EPS, 1.0f); } // clip to [EPS,1]

// weighted log2-dot of one float4 against 4 coefficients
__device__ __forceinline__ float rowdot4(const vf4 v, float c0, float c1, float c2, float c3) {
    float p = c0 * flog2(clampe1(v.x));
    p = fmaf(c1, flog2(clampe1(v.y)), p);
    p = fmaf(c2, flog2(clampe1(v.z)), p);
    p = fmaf(c3, flog2(clampe1(v.w)), p);
    return p;
}

// sum across the 16-lane row cluster
__device__ __forceinline__ float redux16(float p) {
    p += __shfl_xor(p, 1);
    p += __shfl_xor(p, 2);
    p += __shfl_xor(p, 4);
    p += __shfl_xor(p, 8);
    return p;
}

// All-geometric case (the hot case: a_raw==0 -> r==0 -> every step geometric):
//   out(row) = 2^( sum_i c_i * log2(clip(x_i)) )
//   c_0 = prod_{j=0..62}(1-wn_j);  c_k = wn_{k-1} * prod_{j=k..62}(1-wn_j)
// Layout: 16 lanes per row, 1 float4 per lane -> fully coalesced.
// 4 independent grid-stride streams per iteration (64 B/lane in flight) so the
// serial shfl-reduce latency of one stream hides under the other three; main
// loop has no bounds checks (exact division at the bench shape).
__global__ __launch_bounds__(256, 8)
void vln_kernel(const float* __restrict__ x,
                const float* __restrict__ a_raw,
                const float* __restrict__ w_raw,
                float* __restrict__ out, long long B) {
    __shared__ float s_c[64];
    __shared__ float s_wn[64];
    __shared__ float s_av[64];
    __shared__ float s_r[64];
    __shared__ int   s_geo[64];
    __shared__ int   s_allgeo;

    const int tid = threadIdx.x;

    if (tid < 64) {
        const int li = (tid < NSTEP) ? tid : 0;   // pad with a real element
        float w = w_raw[li];
        float wmin = w, wmax = w;
        #pragma unroll
        for (int off = 32; off > 0; off >>= 1) {
            wmin = fminf(wmin, __shfl_down(wmin, off));
            wmax = fmaxf(wmax, __shfl_down(wmax, off));
        }
        wmin = __shfl(wmin, 0);
        wmax = __shfl(wmax, 0);
        const float denom = fmaxf(wmax - wmin, 1e-8f);
        float wn = fminf(fmaxf((w - wmin) / denom, 0.0f), 1.0f);
        float ea = fexp2(-a_raw[li] * 1.4426950408889634f);  // exp(-a)
        float av = 3.0f / (1.0f + ea) - 1.0f;                // sigmoid*3-1
        float ac = fminf(fmaxf(av, EPS), 1.0f - EPS);
        float r  = (1.0f - 2.0f * ac) / (ac * (1.0f - ac));
        int geo  = (fabsf(r) < 0.001f) ? 1 : 0;
        s_wn[tid] = wn;
        s_av[tid] = av;
        s_r[tid]  = r;
        s_geo[tid] = geo;
        unsigned long long m = __ballot(geo != 0 || tid >= NSTEP);
        if (tid == 0) s_allgeo = (m == ~0ULL) ? 1 : 0;

        // suffix products: S_t = prod_{j=t..62}(1-wn_j)  (S_63 = 1)
        float S = (tid < NSTEP) ? (1.0f - wn) : 1.0f;
        #pragma unroll
        for (int off = 1; off < 64; off <<= 1) {
            float o = __shfl_down(S, off);
            if (tid + off < 64) S *= o;
        }
        float wprev = __shfl_up(wn, 1);                  // wn_{t-1}
        s_c[tid] = (tid == 0) ? S : wprev * S;           // c_t
    }
    __syncthreads();

    const long long total4 = B * 16;                     // float4 elements
    const long long stride = (long long)gridDim.x * blockDim.x;
    const long long idx0 = (long long)blockIdx.x * blockDim.x + tid;

    if (s_allgeo) {
        // ---- hot path: dot-product in log2 domain, 16 lanes per row ----
        const int k = tid & 15;                          // colgroup of this lane
        const float c0 = s_c[4 * k + 0];
        const float c1 = s_c[4 * k + 1];
        const float c2 = s_c[4 * k + 2];
        const float c3 = s_c[4 * k + 3];
        const vf4* __restrict__ x4 = (const vf4*)x;

        long long i = idx0;
        // main loop: 4 independent streams, no bounds checks
        for (; i + 3 * stride < total4; i += 4 * stride) {
            const long long i1 = i + stride;
            const long long i2 = i + 2 * stride;
            const long long i3 = i + 3 * stride;
            vf4 v0 = __builtin_nontemporal_load(x4 + i);
            vf4 v1 = __builtin_nontemporal_load(x4 + i1);
            vf4 v2 = __builtin_nontemporal_load(x4 + i2);
            vf4 v3 = __builtin_nontemporal_load(x4 + i3);

            float p0 = rowdot4(v0, c0, c1, c2, c3);
            float p1 = rowdot4(v1, c0, c1, c2, c3);
            float p2 = rowdot4(v2, c0, c1, c2, c3);
            float p3 = rowdot4(v3, c0, c1, c2, c3);

            p0 = redux16(p0);
            p1 = redux16(p1);
            p2 = redux16(p2);
            p3 = redux16(p3);

            if (k == 0) {
                out[i  >> 4] = fexp2(p0);
                out[i1 >> 4] = fexp2(p1);
                out[i2 >> 4] = fexp2(p2);
                out[i3 >> 4] = fexp2(p3);
            }
        }
        // tail (not taken at the bench shape: total4 divides exactly)
        for (; i < total4; i += stride) {
            vf4 v = __builtin_nontemporal_load(x4 + i);
            float p = redux16(rowdot4(v, c0, c1, c2, c3));
            if (k == 0) out[i >> 4] = fexp2(p);
        }
    } else {
        // ---- cold general path: one row per thread, serial scan ----
        for (long long row = idx0; row < B; row += stride) {
            const float4* xr = (const float4*)(x + (size_t)row * 64);
            float Lacc = 0.0f;
            float lin  = 0.0f;
            int use_lin = 0;
            #pragma unroll
            for (int q = 0; q < 16; ++q) {
                float4 v = xr[q];
                float el[4];
                el[0] = flog2(clampe1(v.x));
                el[1] = flog2(clampe1(v.y));
                el[2] = flog2(clampe1(v.z));
                el[3] = flog2(clampe1(v.w));
                #pragma unroll
                for (int j = 0; j < 4; ++j) {
                    const int gidx = 4 * q + j;
                    if (gidx == 0) { Lacc = el[0]; continue; }
                    const int i = gidx - 1;
                    const float wn = s_wn[i];
                    const float lr = el[j];
                    if (s_geo[i]) {
                        Lacc = fmaf(wn, lr - Lacc, Lacc);
                        use_lin = 0;
                    } else {
                        const float r  = s_r[i];
                        const float pa = fexp2(r * Lacc);
                        const float pb = fexp2(r * lr);
                        const float s  = (1.0f - wn) * pa + wn * pb;
                        float z = fexp2(flog2(s) / r);
                        if (i > 0 && (z != z)) z = s_av[i];
                        lin = z; use_lin = 1;
                        Lacc = flog2(clampe1(z));
                    }
                }
            }
            out[row] = use_lin ? lin : fexp2(Lacc);
        }
    }
}

extern "C" void kernel_launch(void* const* d_in, const int* in_sizes, int n_in,
                              void* d_out, int out_size, void* d_ws, size_t ws_size,
                              hipStream_t stream) {
    const float* x     = (const float*)d_in[0];
    const float* a_raw = (const float*)d_in[1];
    const float* w_raw = (const float*)d_in[2];
    float* out = (float*)d_out;
    const long long B = out_size;            // 524288 rows (x is B x 64)
    long long total4 = B * 16;
    int blocks = (int)((total4 + 255) / 256);
    if (blocks > 2048) blocks = 2048;        // 8 blocks/CU x 256 CUs, grid-stride
    vln_kernel<<<blocks, 256, 0, stream>>>(x, a_raw, w_raw, out, B);
}

// Round 2
// 183.599 us; speedup vs baseline: 1.0484x; 1.0040x over previous
//
#include <hip/hip_runtime.h>

#define EPS 1e-6f
#define NSTEP 63   // L = N-1 aggregation steps

typedef float vf4 __attribute__((ext_vector_type(4)));

// gfx950 builtins (avoid math.h macro clashes):
__device__ __forceinline__ float flog2(float x) { return __builtin_amdgcn_logf(x); }   // v_log_f32 = log2
__device__ __forceinline__ float fexp2(float x) { return __builtin_amdgcn_exp2f(x); }  // v_exp_f32 = 2^x
__device__ __forceinline__ float clampe1(float x) { return __builtin_amdgcn_fmed3f(x, EPS, 1.0f); } // clip to [EPS,1]

// weighted log2-dot of one float4 against 4 coefficients
__device__ __forceinline__ float rowdot4(const vf4 v, float c0, float c1, float c2, float c3) {
    float p = c0 * flog2(clampe1(v.x));
    p = fmaf(c1, flog2(clampe1(v.y)), p);
    p = fmaf(c2, flog2(clampe1(v.z)), p);
    p = fmaf(c3, flog2(clampe1(v.w)), p);
    return p;
}

// --- DPP 16-lane full-reduce: rotate-add butterfly, pure VALU, no ds ops ---
// row_ror:N ctrl encoding = 0x120 + N (DPP row = 16 lanes on CDNA).
// After adding rotations by 1,2,4,8 every lane holds the sum of its 16-lane row.
template <int CTRL>
__device__ __forceinline__ float dpp_radd(float p) {
    int t = __builtin_amdgcn_update_dpp(0, __float_as_int(p), CTRL, 0xF, 0xF, true);
    return p + __int_as_float(t);
}
__device__ __forceinline__ float redux16_dpp(float p) {
    p = dpp_radd<0x121>(p);   // row_ror:1
    p = dpp_radd<0x122>(p);   // row_ror:2
    p = dpp_radd<0x124>(p);   // row_ror:4
    p = dpp_radd<0x128>(p);   // row_ror:8
    return p;
}

// shfl-based reduce kept for the (never-taken at bench shape) divergent tail
__device__ __forceinline__ float redux16_shfl(float p) {
    p += __shfl_xor(p, 1);
    p += __shfl_xor(p, 2);
    p += __shfl_xor(p, 4);
    p += __shfl_xor(p, 8);
    return p;
}

// All-geometric case (the hot case: a_raw==0 -> r==0 -> every step geometric):
//   out(row) = 2^( sum_i c_i * log2(clip(x_i)) )
//   c_0 = prod_{j=0..62}(1-wn_j);  c_k = wn_{k-1} * prod_{j=k..62}(1-wn_j)
// Layout: 16 lanes per row, 1 float4 per lane -> fully coalesced.
// 4 independent grid-stride streams per iteration (64 B/lane in flight);
// reductions via DPP (no lgkmcnt in the hot loop); main loop has no bounds
// checks (exact division at the bench shape).
__global__ __launch_bounds__(256, 8)
void vln_kernel(const float* __restrict__ x,
                const float* __restrict__ a_raw,
                const float* __restrict__ w_raw,
                float* __restrict__ out, long long B) {
    __shared__ float s_c[64];
    __shared__ float s_wn[64];
    __shared__ float s_av[64];
    __shared__ float s_r[64];
    __shared__ int   s_geo[64];
    __shared__ int   s_allgeo;

    const int tid = threadIdx.x;

    if (tid < 64) {
        const int li = (tid < NSTEP) ? tid : 0;   // pad with a real element
        float w = w_raw[li];
        float wmin = w, wmax = w;
        #pragma unroll
        for (int off = 32; off > 0; off >>= 1) {
            wmin = fminf(wmin, __shfl_down(wmin, off));
            wmax = fmaxf(wmax, __shfl_down(wmax, off));
        }
        wmin = __shfl(wmin, 0);
        wmax = __shfl(wmax, 0);
        const float denom = fmaxf(wmax - wmin, 1e-8f);
        float wn = fminf(fmaxf((w - wmin) / denom, 0.0f), 1.0f);
        float ea = fexp2(-a_raw[li] * 1.4426950408889634f);  // exp(-a)
        float av = 3.0f / (1.0f + ea) - 1.0f;                // sigmoid*3-1
        float ac = fminf(fmaxf(av, EPS), 1.0f - EPS);
        float r  = (1.0f - 2.0f * ac) / (ac * (1.0f - ac));
        int geo  = (fabsf(r) < 0.001f) ? 1 : 0;
        s_wn[tid] = wn;
        s_av[tid] = av;
        s_r[tid]  = r;
        s_geo[tid] = geo;
        unsigned long long m = __ballot(geo != 0 || tid >= NSTEP);
        if (tid == 0) s_allgeo = (m == ~0ULL) ? 1 : 0;

        // suffix products: S_t = prod_{j=t..62}(1-wn_j)  (S_63 = 1)
        float S = (tid < NSTEP) ? (1.0f - wn) : 1.0f;
        #pragma unroll
        for (int off = 1; off < 64; off <<= 1) {
            float o = __shfl_down(S, off);
            if (tid + off < 64) S *= o;
        }
        float wprev = __shfl_up(wn, 1);                  // wn_{t-1}
        s_c[tid] = (tid == 0) ? S : wprev * S;           // c_t
    }
    __syncthreads();

    const long long total4 = B * 16;                     // float4 elements
    const long long stride = (long long)gridDim.x * blockDim.x;
    const long long idx0 = (long long)blockIdx.x * blockDim.x + tid;

    if (s_allgeo) {
        // ---- hot path: dot-product in log2 domain, 16 lanes per row ----
        const int k = tid & 15;                          // colgroup of this lane
        const float c0 = s_c[4 * k + 0];
        const float c1 = s_c[4 * k + 1];
        const float c2 = s_c[4 * k + 2];
        const float c3 = s_c[4 * k + 3];
        const vf4* __restrict__ x4 = (const vf4*)x;

        // per-stream pointers; advance by 4*stride each iteration
        const vf4* p0p = x4 + idx0;
        const vf4* p1p = p0p + stride;
        const vf4* p2p = p1p + stride;
        const vf4* p3p = p2p + stride;
        long long i = idx0;
        const long long rstep = (4 * stride) >> 4;       // row advance per iter
        long long r0 = idx0 >> 4;                        // row of stream 0 (valid when k==0)
        const long long rs = stride >> 4;                // rows between streams

        for (; i + 3 * stride < total4; i += 4 * stride) {
            vf4 v0 = __builtin_nontemporal_load(p0p);
            vf4 v1 = __builtin_nontemporal_load(p1p);
            vf4 v2 = __builtin_nontemporal_load(p2p);
            vf4 v3 = __builtin_nontemporal_load(p3p);
            p0p += 4 * stride; p1p += 4 * stride;
            p2p += 4 * stride; p3p += 4 * stride;

            float p0 = rowdot4(v0, c0, c1, c2, c3);
            float p1 = rowdot4(v1, c0, c1, c2, c3);
            float p2 = rowdot4(v2, c0, c1, c2, c3);
            float p3 = rowdot4(v3, c0, c1, c2, c3);

            p0 = redux16_dpp(p0);
            p1 = redux16_dpp(p1);
            p2 = redux16_dpp(p2);
            p3 = redux16_dpp(p3);

            if (k == 0) {
                out[r0         ] = fexp2(p0);
                out[r0 +     rs] = fexp2(p1);
                out[r0 + 2 * rs] = fexp2(p2);
                out[r0 + 3 * rs] = fexp2(p3);
            }
            r0 += rstep;
        }
        // tail (not taken at the bench shape: total4 divides exactly)
        for (; i < total4; i += stride) {
            vf4 v = __builtin_nontemporal_load(x4 + i);
            float p = redux16_shfl(rowdot4(v, c0, c1, c2, c3));
            if (k == 0) out[i >> 4] = fexp2(p);
        }
    } else {
        // ---- cold general path: one row per thread, serial scan ----
        for (long long row = idx0; row < B; row += stride) {
            const float4* xr = (const float4*)(x + (size_t)row * 64);
            float Lacc = 0.0f;
            float lin  = 0.0f;
            int use_lin = 0;
            #pragma unroll
            for (int q = 0; q < 16; ++q) {
                float4 v = xr[q];
                float el[4];
                el[0] = flog2(clampe1(v.x));
                el[1] = flog2(clampe1(v.y));
                el[2] = flog2(clampe1(v.z));
                el[3] = flog2(clampe1(v.w));
                #pragma unroll
                for (int j = 0; j < 4; ++j) {
                    const int gidx = 4 * q + j;
                    if (gidx == 0) { Lacc = el[0]; continue; }
                    const int i = gidx - 1;
                    const float wn = s_wn[i];
                    const float lr = el[j];
                    if (s_geo[i]) {
                        Lacc = fmaf(wn, lr - Lacc, Lacc);
                        use_lin = 0;
                    } else {
                        const float r  = s_r[i];
                        const float pa = fexp2(r * Lacc);
                        const float pb = fexp2(r * lr);
                        const float s  = (1.0f - wn) * pa + wn * pb;
                        float z = fexp2(flog2(s) / r);
                        if (i > 0 && (z != z)) z = s_av[i];
                        lin = z; use_lin = 1;
                        Lacc = flog2(clampe1(z));
                    }
                }
            }
            out[row] = use_lin ? lin : fexp2(Lacc);
        }
    }
}

extern "C" void kernel_launch(void* const* d_in, const int* in_sizes, int n_in,
                              void* d_out, int out_size, void* d_ws, size_t ws_size,
                              hipStream_t stream) {
    const float* x     = (const float*)d_in[0];
    const float* a_raw = (const float*)d_in[1];
    const float* w_raw = (const float*)d_in[2];
    float* out = (float*)d_out;
    const long long B = out_size;            // 524288 rows (x is B x 64)
    long long total4 = B * 16;
    int blocks = (int)((total4 + 255) / 256);
    if (blocks > 2048) blocks = 2048;        // 8 blocks/CU x 256 CUs, grid-stride
    vln_kernel<<<blocks, 256, 0, stream>>>(x, a_raw, w_raw, out, B);
}